// Round 27
// baseline (200.370 us; speedup 1.0000x reference)
//
#include <hip/hip_runtime.h>
#include <math.h>

constexpr int B_ = 16, E_ = 256, NC_ = 8, Q_ = 40, H_ = 64, W_ = 64, HW_ = 4096;
constexpr int NH_ = 8, HD_ = 32, OF_ = 64;
constexpr int KP1_ = 320;          // padded K for gemm1 (E+NC=264 -> 320)
constexpr int NPART_ = 32;         // attention partials per (b,head)
constexpr int CH2_ = 32;           // attention chunks (1 wave each, 128 px)
constexpr int KVS_ = 512;          // kv buffer row stride (k 0..255, v 256..511)

typedef __attribute__((ext_vector_type(8))) unsigned short us8;
typedef __attribute__((ext_vector_type(8))) short s8b;     // bf16 MFMA frag (K=32)
typedef __attribute__((ext_vector_type(4))) short s4b;     // bf16 MFMA frag (K=16)
typedef __attribute__((ext_vector_type(4))) float f32x4;

__device__ __forceinline__ float gelu_f(float x) {
  return 0.5f * x * (1.0f + erff(x * 0.70710678118654752f));
}
__device__ __forceinline__ float bf2f(unsigned short u) {
  return __uint_as_float(((unsigned int)u) << 16);
}
__device__ __forceinline__ unsigned short f2bf(float f) {
  unsigned int u = __float_as_uint(f);
  u = u + 0x7fff + ((u >> 16) & 1);  // RNE
  return (unsigned short)(u >> 16);
}
// pack two f32 -> one u32 of 2 bf16 (lo=a, hi=b), RNE
__device__ __forceinline__ unsigned int cvtpk_bf16(float a, float b) {
  unsigned int r;
  asm("v_cvt_pk_bf16_f32 %0, %1, %2" : "=v"(r) : "v"(a), "v"(b));
  return r;
}
// async global->LDS 16B; LDS dest linear in lane (wave base + lane*16)
__device__ __forceinline__ void gl_lds16(const unsigned short* g, unsigned short* l) {
  __builtin_amdgcn_global_load_lds(
      (const __attribute__((address_space(1))) unsigned int*)g,
      (__attribute__((address_space(3))) unsigned int*)l, 16, 0, 0);
}

// ---------- misc1: wprep U q-branch(LN+GEMM) U tvec, range-dispatched ----------
// (xcat_t transpose removed -- fused into hgemm1f's A-staging)
__global__ __launch_bounds__(256)
void misc1(const float* __restrict__ w1, const float* __restrict__ w2,
           const float* __restrict__ wk, const float* __restrict__ wv,
           const float* __restrict__ kb, const float* __restrict__ vb,
           unsigned short* __restrict__ o1, unsigned short* __restrict__ o2,
           unsigned short* __restrict__ okv, float* __restrict__ kvbias,
           const float* __restrict__ img, const float* __restrict__ msk,
           const float* __restrict__ qp, const float* __restrict__ ln_g,
           const float* __restrict__ ln_b, const float* __restrict__ qw,
           const float* __restrict__ qb, float* __restrict__ qbuf,
           const float* __restrict__ icw, const float* __restrict__ icb,
           const float* __restrict__ mcw, const float* __restrict__ mcb,
           float* __restrict__ timg, float* __restrict__ tmsk) {
  __shared__ __align__(16) float smem[64 * 65];
  const int bid = blockIdx.x;
  const int t = threadIdx.x;
  if (bid < 4 * KP1_) {
    // ---- wprep ----
    const int which = bid / KP1_;
    const int k = bid % KP1_;
    const int n = t;
    if (which == 0) {
      float v = (k < 264) ? w1[(size_t)k * E_ + n] : 0.f;
      o1[(size_t)n * KP1_ + k] = f2bf(v);
    } else if (k < 256) {
      if (which == 1) {
        o2[(size_t)n * 256 + k] = f2bf(w2[(size_t)k * E_ + n]);
      } else if (which == 2) {
        okv[(size_t)n * 256 + k] = f2bf(wk[(size_t)k * E_ + n]);
        if (k == 0) kvbias[n] = kb[n];
      } else {
        okv[(size_t)(256 + n) * 256 + k] = f2bf(wv[(size_t)k * E_ + n]);
        if (k == 0) kvbias[256 + n] = vb[n];
      }
    }
  } else if (bid < 4 * KP1_ + 640) {
    // ---- q branch: LN + Linear ----
    const int row = bid - 4 * KP1_;
    float* xs = smem;
    float* rs = smem + 272;
    float* rs2 = smem + 280;
    float* sm = smem + 288;
    float x = qp[(size_t)row * E_ + t];
    float s = x, s2 = x * x;
    #pragma unroll
    for (int o = 32; o > 0; o >>= 1) { s += __shfl_down(s, o, 64); s2 += __shfl_down(s2, o, 64); }
    if ((t & 63) == 0) { rs[t >> 6] = s; rs2[t >> 6] = s2; }
    __syncthreads();
    if (t == 0) {
      float S = rs[0] + rs[1] + rs[2] + rs[3];
      float S2 = rs2[0] + rs2[1] + rs2[2] + rs2[3];
      float m = S * (1.0f / E_);
      sm[0] = m;
      sm[1] = rsqrtf(S2 * (1.0f / E_) - m * m + 1e-5f);
    }
    __syncthreads();
    x = (x - sm[0]) * sm[1] * ln_g[t] + ln_b[t];
    xs[t] = x;
    __syncthreads();
    float acc = qb[t];
    #pragma unroll 8
    for (int c = 0; c < E_; ++c) acc += xs[c] * qw[(size_t)c * E_ + t];
    qbuf[(size_t)row * E_ + t] = acc;
  } else {
    // ---- tvec: float4 over 4 pixels/lane ----
    const int id = bid - (4 * KP1_ + 640);
    const int b = id >> 4;
    const int chunk = id & 15;
    const int lane = t & 63, seg = t >> 6;
    const int p = chunk * 256 + lane * 4;
    f32x4 (*red)[64] = (f32x4(*)[64])smem;
    f32x4 s = (f32x4){0.f, 0.f, 0.f, 0.f};
    const float* ib = img + (size_t)b * E_ * HW_ + p;
    #pragma unroll 8
    for (int e = seg * 64; e < seg * 64 + 64; ++e) {
      const f32x4 v = *(const f32x4*)(ib + (size_t)e * HW_);
      s += v * icw[e];
    }
    red[seg][lane] = s;
    __syncthreads();
    if (seg == 0) {
      f32x4 tot = red[0][lane] + red[1][lane] + red[2][lane] + red[3][lane];
      #pragma unroll
      for (int j = 0; j < 4; ++j) tot[j] += icb[0];
      *(f32x4*)(timg + (size_t)b * HW_ + p) = tot;
      f32x4 s2;
      #pragma unroll
      for (int j = 0; j < 4; ++j) s2[j] = mcb[0];
      const float* mb = msk + (size_t)b * NC_ * HW_ + p;
      #pragma unroll
      for (int c = 0; c < NC_; ++c) {
        const f32x4 mv = *(const f32x4*)(mb + (size_t)c * HW_);
        s2 += mv * mcw[c];
      }
      *(f32x4*)(tmsk + (size_t)b * HW_ + p) = s2;
    }
  }
}

// ---------- hgemm: round-10 body + XCD-aware A-panel locality remap ----------
template<int EPI, int KP, int OSTR, int NN>
__global__ __launch_bounds__(256, 4)
void hgemm(const unsigned short* __restrict__ A, const unsigned short* __restrict__ Wt,
           const float* __restrict__ bias, unsigned short* __restrict__ out) {
  constexpr int NT = KP / 64;                     // 4 or 5 K-steps
  __shared__ __align__(16) unsigned short As[128 * 64];  // 16 KB
  __shared__ __align__(16) unsigned short Bs[64 * 64];   // 8 KB
  const int t = threadIdx.x;
  const int bid = blockIdx.x;
  const int xcd = bid & 7;
  const int grp = bid >> 3;
  const int m0 = ((grp / NN) * 8 + xcd) * 128;
  const int n0 = (grp % NN) * 64;
  const int w = t >> 6, lane = t & 63;
  const int c = lane & 15, g = lane >> 4;
  const int wm = (w & 1) * 64, wn = (w >> 1) * 32;

  f32x4 acc[4][2];
  #pragma unroll
  for (int i = 0; i < 4; ++i)
    #pragma unroll
    for (int j = 0; j < 2; ++j) acc[i][j] = (f32x4){0.f, 0.f, 0.f, 0.f};

  for (int kt = 0; kt < NT; ++kt) {
    if (kt) __syncthreads();
    #pragma unroll
    for (int i = 0; i < 4; ++i) {
      const int f = i * 256 + t;
      const int row = f >> 3, s = f & 7;
      gl_lds16(A + (size_t)(m0 + row) * KP + kt * 64 + (s ^ (row & 7)) * 8, As + f * 8);
    }
    #pragma unroll
    for (int i = 0; i < 2; ++i) {
      const int f = i * 256 + t;
      const int row = f >> 3, s = f & 7;
      gl_lds16(Wt + (size_t)(n0 + row) * KP + kt * 64 + (s ^ (row & 7)) * 8, Bs + f * 8);
    }
    __syncthreads();
    #pragma unroll
    for (int ks = 0; ks < 2; ++ks) {
      s8b af[4], bf[2];
      #pragma unroll
      for (int mf = 0; mf < 4; ++mf) {
        const int row = wm + mf * 16 + c;
        af[mf] = *(const s8b*)&As[row * 64 + ((ks * 4 + g) ^ (row & 7)) * 8];
      }
      #pragma unroll
      for (int nf = 0; nf < 2; ++nf) {
        const int row = wn + nf * 16 + c;
        bf[nf] = *(const s8b*)&Bs[row * 64 + ((ks * 4 + g) ^ (row & 7)) * 8];
      }
      #pragma unroll
      for (int mf = 0; mf < 4; ++mf)
        #pragma unroll
        for (int nf = 0; nf < 2; ++nf)
          acc[mf][nf] = __builtin_amdgcn_mfma_f32_16x16x32_bf16(af[mf], bf[nf], acc[mf][nf], 0, 0, 0);
    }
  }

  float bv[2];
  #pragma unroll
  for (int nf = 0; nf < 2; ++nf) bv[nf] = bias[n0 + wn + nf * 16 + c];
  __syncthreads();
  #pragma unroll
  for (int mf = 0; mf < 4; ++mf)
    #pragma unroll
    for (int r = 0; r < 4; ++r) {
      const int row = wm + mf * 16 + g * 4 + r;
      #pragma unroll
      for (int nf = 0; nf < 2; ++nf) {
        float v = acc[mf][nf][r] + bv[nf];
        if constexpr (EPI == 0) v = gelu_f(v);
        As[row * 64 + wn + nf * 16 + c] = f2bf(v);
      }
    }
  __syncthreads();
  #pragma unroll
  for (int i = 0; i < 4; ++i) {
    const int f = i * 256 + t;
    const int row = f >> 3, sl = f & 7;
    *(us8*)(out + (size_t)(m0 + row) * OSTR + n0 + sl * 8) = *(const us8*)&As[row * 64 + sl * 8];
  }
}

// ---------- hgemm1f: gemm1 with FUSED on-the-fly transpose of img/msk ----------
// A-source is fp32 [k][px]. As uses a PADDED row (66 shorts = 132B) instead of
// the XOR swizzle: write quad-bank = (4*lane + j + 4*kg) % 32 -> all 32 banks
// covered per 8 lanes (structural floor; was ~16-way with 128B rows, 4.45M
// SQ_LDS_BANK_CONFLICT). Reads walk banks by 1/row (~2-way, near-free).
__global__ __launch_bounds__(256, 4)
void hgemm1f(const float* __restrict__ img, const float* __restrict__ msk,
             const unsigned short* __restrict__ Wt,
             const float* __restrict__ bias, unsigned short* __restrict__ out) {
  constexpr int KP = KP1_;          // 320
  constexpr int NT = 5;
  constexpr int NN = 4;
  constexpr int ASTR = 66;          // padded As row stride (shorts)
  __shared__ __align__(16) unsigned short As[128 * ASTR];  // 16.5 KB
  __shared__ __align__(16) unsigned short Bs[64 * 64];     // 8 KB
  const int t = threadIdx.x;
  const int bid = blockIdx.x;
  const int xcd = bid & 7;
  const int grp = bid >> 3;
  const int m0 = ((grp / NN) * 8 + xcd) * 128;
  const int n0 = (grp % NN) * 64;
  const int b = m0 >> 12;           // batch (128 | 4096, never crosses)
  const int px0 = m0 & 4095;        // pixel base within batch
  const int w = t >> 6, lane = t & 63;
  const int c = lane & 15, g = lane >> 4;
  const int wm = (w & 1) * 64, wn = (w >> 1) * 32;
  const int pg = t & 31;            // 4-px group (0..31)
  const int kg = t >> 5;            // 8-k group (0..7)

  f32x4 acc[4][2];
  #pragma unroll
  for (int i = 0; i < 4; ++i)
    #pragma unroll
    for (int j = 0; j < 2; ++j) acc[i][j] = (f32x4){0.f, 0.f, 0.f, 0.f};

  for (int kt = 0; kt < NT; ++kt) {
    if (kt) __syncthreads();
    // B staging (async, bf16 weights prepped by wprep; keeps XOR swizzle)
    #pragma unroll
    for (int i = 0; i < 2; ++i) {
      const int f = i * 256 + t;
      const int row = f >> 3, s = f & 7;
      gl_lds16(Wt + (size_t)(n0 + row) * KP + kt * 64 + (s ^ (row & 7)) * 8, Bs + f * 8);
    }
    // A staging: 8 k-rows x 4 px per thread, fp32 -> bf16, transposed into As
    f32x4 ar[8];
    #pragma unroll
    for (int i = 0; i < 8; ++i) {
      const int k = kt * 64 + kg * 8 + i;
      if (k < 256)
        ar[i] = *(const f32x4*)(img + ((size_t)b * E_ + k) * HW_ + px0 + pg * 4);
      else if (k < 264)
        ar[i] = *(const f32x4*)(msk + ((size_t)b * NC_ + (k - 256)) * HW_ + px0 + pg * 4);
      else
        ar[i] = (f32x4){0.f, 0.f, 0.f, 0.f};   // zero pad (NaN-safe)
    }
    #pragma unroll
    for (int j = 0; j < 4; ++j) {
      const int px = pg * 4 + j;
      uint4 pk;
      pk.x = cvtpk_bf16(ar[0][j], ar[1][j]);
      pk.y = cvtpk_bf16(ar[2][j], ar[3][j]);
      pk.z = cvtpk_bf16(ar[4][j], ar[5][j]);
      pk.w = cvtpk_bf16(ar[6][j], ar[7][j]);
      *(uint4*)&As[px * ASTR + kg * 8] = pk;
    }
    __syncthreads();
    #pragma unroll
    for (int ks = 0; ks < 2; ++ks) {
      s8b af[4], bf[2];
      #pragma unroll
      for (int mf = 0; mf < 4; ++mf) {
        const int row = wm + mf * 16 + c;
        af[mf] = *(const s8b*)&As[row * ASTR + (ks * 4 + g) * 8];
      }
      #pragma unroll
      for (int nf = 0; nf < 2; ++nf) {
        const int row = wn + nf * 16 + c;
        bf[nf] = *(const s8b*)&Bs[row * 64 + ((ks * 4 + g) ^ (row & 7)) * 8];
      }
      #pragma unroll
      for (int mf = 0; mf < 4; ++mf)
        #pragma unroll
        for (int nf = 0; nf < 2; ++nf)
          acc[mf][nf] = __builtin_amdgcn_mfma_f32_16x16x32_bf16(af[mf], bf[nf], acc[mf][nf], 0, 0, 0);
    }
  }

  float bv[2];
  #pragma unroll
  for (int nf = 0; nf < 2; ++nf) bv[nf] = bias[n0 + wn + nf * 16 + c];
  __syncthreads();
  #pragma unroll
  for (int mf = 0; mf < 4; ++mf)
    #pragma unroll
    for (int r = 0; r < 4; ++r) {
      const int row = wm + mf * 16 + g * 4 + r;
      #pragma unroll
      for (int nf = 0; nf < 2; ++nf) {
        float v = gelu_f(acc[mf][nf][r] + bv[nf]);
        As[row * 64 + wn + nf * 16 + c] = f2bf(v);   // 64-stride scratch reuse
      }
    }
  __syncthreads();
  #pragma unroll
  for (int i = 0; i < 4; ++i) {
    const int f = i * 256 + t;
    const int row = f >> 3, sl = f & 7;
    *(us8*)(out + (size_t)(m0 + row) * 256 + n0 + sl * 8) = *(const us8*)&As[row * 64 + sl * 8];
  }
}

// ---------- rowstats ----------
__global__ __launch_bounds__(256)
void rowstats(const unsigned short* __restrict__ X, float* __restrict__ mean,
              float* __restrict__ rstd) {
  const int row = blockIdx.x * 4 + (threadIdx.x >> 6);
  const int lane = threadIdx.x & 63;
  const uint2 u = *(const uint2*)(X + (size_t)row * E_ + lane * 4);
  float a = bf2f(u.x & 0xffff), b = bf2f(u.x >> 16);
  float c = bf2f(u.y & 0xffff), d = bf2f(u.y >> 16);
  float s = a + b + c + d;
  float s2 = a * a + b * b + c * c + d * d;
  #pragma unroll
  for (int o = 32; o > 0; o >>= 1) { s += __shfl_down(s, o, 64); s2 += __shfl_down(s2, o, 64); }
  if (lane == 0) {
    const float m = s * (1.0f / E_);
    mean[row] = m;
    rstd[row] = rsqrtf(s2 * (1.0f / E_) - m * m + 1e-5f);
  }
}

// ---------- attvec_p: parallel partials for att_image/att_mask ----------
__global__ __launch_bounds__(256)
void attvec_p(const float* __restrict__ timg, const float* __restrict__ tmsk,
              const float* __restrict__ ipw, const float* __restrict__ mpw,
              float* __restrict__ part) {
  const int chunk = blockIdx.x;
  const int b = blockIdx.y;
  const int mat = blockIdx.z;
  const int o = threadIdx.x & 63, ps = threadIdx.x >> 6;
  const float* tv = (mat ? tmsk : timg) + (size_t)b * HW_ + chunk * 256;
  const float* wp = (mat ? mpw : ipw) + (size_t)chunk * 256 * OF_;
  float s = 0.f;
  #pragma unroll 8
  for (int i = 0; i < 64; ++i) {
    const int p = ps * 64 + i;
    s += tv[p] * wp[(size_t)p * OF_ + o];
  }
  __shared__ float red[4][64];
  red[ps][o] = s;
  __syncthreads();
  if (ps == 0)
    part[(((size_t)b * 2 + mat) * 16 + chunk) * OF_ + o] =
        red[0][o] + red[1][o] + red[2][o] + red[3][o];
}

// ---------- attbias2: reduce partials -> ai/am in LDS -> A1/asd/bsd ----------
__global__ __launch_bounds__(256)
void attbias2(const float* __restrict__ part, const float* __restrict__ ipb,
              const float* __restrict__ mpb, const float* __restrict__ alpha,
              const float* __restrict__ beta, float* __restrict__ A1,
              float* __restrict__ asd, float* __restrict__ bsd) {
  __shared__ float aiL[64], amL[64];
  const int b = blockIdx.x;
  const int t = threadIdx.x;
  if (t < 128) {
    const int mat = t >> 6, o = t & 63;
    float v = (mat ? mpb : ipb)[o];
    #pragma unroll
    for (int c = 0; c < 16; ++c)
      v += part[(((size_t)b * 2 + mat) * 16 + c) * OF_ + o];
    if (mat) amL[o] = v; else aiL[o] = v;
  }
  __syncthreads();
  const float scl = 0.17677669529663687f;  // 1/sqrt(32)
  #pragma unroll
  for (int it = 0; it < 16; ++it) {
    const int p = it * 256 + t;
    A1[(size_t)b * HW_ + p] = aiL[p >> 6] * amL[p & 63] * alpha[p] * scl;
    if (b == 0) {
      asd[p] = alpha[p] * scl;
      bsd[p] = beta[p] * scl;
    }
  }
}

// ---------- dwconv_ln4: channel-split blocks + ASYNC LDS halo staging ----------
__global__ __launch_bounds__(256, 4)
void dwconv_ln4(const unsigned short* __restrict__ X2, const float* __restrict__ mean,
                const float* __restrict__ rstd, const float* __restrict__ g2,
                const float* __restrict__ b2, const float* __restrict__ wgt,
                const float* __restrict__ cbias, unsigned short* __restrict__ out) {
  __shared__ __align__(16) unsigned short xsh[108 * 128];  // 27648 B
  __shared__ float msh[108], rsh[108];
  const int t = threadIdx.x;
  const int w0 = blockIdx.x * 16;
  const int h0 = blockIdx.y * 4;
  const int b = blockIdx.z >> 1;
  const int dh = blockIdx.z & 1;
  const int dl = t & 127;            // local channel
  const int cg = t >> 7;             // col-group (8 cols each)
  const int dgl = dh * 128 + dl;     // global channel
  const size_t bbase = (size_t)b * HW_;
  for (int f = t; f < 108 * 16; f += 256) {
    const int pix = f >> 4, sl = f & 15;
    const int s = pix / 18, i = pix % 18;
    const int hh = h0 - 1 + s, ww = w0 - 1 + i;
    const bool ok = (hh >= 0 && hh < H_ && ww >= 0 && ww < W_);
    const size_t p = ok ? (bbase + hh * W_ + ww) : bbase;   // clamp; never read if !ok
    gl_lds16(X2 + p * E_ + dh * 128 + sl * 8, &xsh[f * 8]);
  }
  if (t < 108) {
    const int pix = t;
    const int s = pix / 18, i = pix % 18;
    const int hh = h0 - 1 + s, ww = w0 - 1 + i;
    if (hh >= 0 && hh < H_ && ww >= 0 && ww < W_) {
      const size_t p = bbase + hh * W_ + ww;
      msh[pix] = mean[p];
      rsh[pix] = rstd[p];
    } else {
      msh[pix] = 0.f;
      rsh[pix] = 0.f;
    }
  }
  float wq[9];
  #pragma unroll
  for (int i = 0; i < 9; ++i) wq[i] = wgt[i * E_ + dgl];
  const float gg = g2[dgl], bb = b2[dgl], bias = cbias[dgl];
  __syncthreads();   // drains gl_lds16 (vmcnt) + msh/rsh writes
  float o[4][8];
  #pragma unroll
  for (int oy = 0; oy < 4; ++oy)
    #pragma unroll
    for (int j = 0; j < 8; ++j) o[oy][j] = bias;
  #pragma unroll
  for (int s = 0; s < 6; ++s) {
    const int hh = h0 - 1 + s;
    if (hh < 0 || hh >= H_) continue;
    float r[10];
    #pragma unroll
    for (int i = 0; i < 10; ++i) {
      const int rc = cg * 8 + i;          // region col 0..17
      const int ww = w0 - 1 + rc;
      if (ww >= 0 && ww < W_) {
        const int pix = s * 18 + rc;
        const float x = bf2f(xsh[pix * 128 + dl]);
        r[i] = (x - msh[pix]) * rsh[pix] * gg + bb;
      } else r[i] = 0.f;
    }
    #pragma unroll
    for (int ky = 0; ky < 3; ++ky) {
      const int oy = s - ky;
      if (oy < 0 || oy >= 4) continue;
      const float w_0 = wq[ky * 3], w_1 = wq[ky * 3 + 1], w_2 = wq[ky * 3 + 2];
      #pragma unroll
      for (int j = 0; j < 8; ++j)
        o[oy][j] += r[j] * w_0 + r[j + 1] * w_1 + r[j + 2] * w_2;
    }
  }
  #pragma unroll
  for (int oy = 0; oy < 4; ++oy) {
    const size_t ob_ = bbase + (h0 + oy) * W_ + w0 + cg * 8;
    #pragma unroll
    for (int j = 0; j < 8; ++j) out[(ob_ + j) * E_ + dgl] = f2bf(o[oy][j]);
  }
}

#if __has_builtin(__builtin_amdgcn_mfma_f32_16x16x16bf16_1k)
#define HAVE_MFMA16 1
#else
#define HAVE_MFMA16 0
#endif

// ---------- MFMA flash attention: O^T formulation + XCD-local head groups ----------
__global__ __launch_bounds__(64)
void attn_mfma1w(const float* __restrict__ qbuf, const unsigned short* __restrict__ kv,
                 const float* __restrict__ masks,
                 const float* __restrict__ A1, const float* __restrict__ asd,
                 const float* __restrict__ bsd, const float* __restrict__ cw,
                 const float* __restrict__ cb,
                 float* __restrict__ pacc, float* __restrict__ pm, float* __restrict__ pl) {
  const int bid = blockIdx.x;
  const int xcd = bid & 7;
  const int n = (bid >> 3) & 7;
  const int pb = ((bid >> 6) << 3) | xcd;   // 0..511 = (ch,b)
  const int ch = pb & 31;
  const int b = pb >> 5;
  const int lane = threadIdx.x;
  const int c = lane & 15, g = lane >> 4;
  __shared__ __align__(16) unsigned short Vt[32 * 72];
#if !HAVE_MFMA16
  __shared__ __align__(16) unsigned short Pl[48 * 72];
#endif

  const size_t bhw = (size_t)b * HW_;
  const int koff = n * HD_;
  const int voff = 256 + koff;
  const int pbase = ch * 128;

  s8b kf2[2][4];
  #pragma unroll
  for (int tile = 0; tile < 2; ++tile) {
    const int p0 = pbase + tile * 64;
    #pragma unroll
    for (int mt = 0; mt < 4; ++mt)
      kf2[tile][mt] = *(const s8b*)(kv + (bhw + p0 + mt * 16 + c) * KVS_ + koff + g * 8);
  }

  s8b qf[3];
  float cwq[3], cbq[3];
  int cls[3];
  #pragma unroll
  for (int nt = 0; nt < 3; ++nt) {
    const int q = nt * 16 + c;
    unsigned short tmp[8];
    if (q < Q_) {
      const float* qp = qbuf + ((size_t)b * Q_ + q) * E_ + koff + g * 8;
      const float4 f0 = *(const float4*)qp;
      const float4 f1 = *(const float4*)(qp + 4);
      tmp[0] = f2bf(f0.x); tmp[1] = f2bf(f0.y); tmp[2] = f2bf(f0.z); tmp[3] = f2bf(f0.w);
      tmp[4] = f2bf(f1.x); tmp[5] = f2bf(f1.y); tmp[6] = f2bf(f1.z); tmp[7] = f2bf(f1.w);
      cwq[nt] = cw[q]; cbq[nt] = cb[q];
    } else {
      #pragma unroll
      for (int i = 0; i < 8; ++i) tmp[i] = 0;
      cwq[nt] = 0.f; cbq[nt] = 0.f;
    }
    qf[nt] = *(const s8b*)tmp;
    cls[nt] = min(q / 5, NC_ - 1);
  }

  f32x4 acc_oT[3][2];
  #pragma unroll
  for (int qt = 0; qt < 3; ++qt)
    #pragma unroll
    for (int dt = 0; dt < 2; ++dt) acc_oT[qt][dt] = (f32x4){0.f, 0.f, 0.f, 0.f};
  float m_r[3] = {-1e30f, -1e30f, -1e30f};
  float l_r[3] = {0.f, 0.f, 0.f};
  float scv[3] = {1.f, 1.f, 1.f};

  #pragma unroll
  for (int tile = 0; tile < 2; ++tile) {
    const int p0 = pbase + tile * 64;
    us8 vr[4];
    #pragma unroll
    for (int cp = 0; cp < 4; ++cp)
      vr[cp] = *(const us8*)(kv + (bhw + p0 + lane) * KVS_ + voff + cp * 8);
    f32x4 sa[3][4];
    __builtin_amdgcn_s_setprio(1);
    #pragma unroll
    for (int nt = 0; nt < 3; ++nt)
      #pragma unroll
      for (int mt = 0; mt < 4; ++mt)
        sa[nt][mt] = __builtin_amdgcn_mfma_f32_16x16x32_bf16(kf2[tile][mt], qf[nt],
                     (f32x4){0.f, 0.f, 0.f, 0.f}, 0, 0, 0);
    __builtin_amdgcn_s_setprio(0);
    #pragma unroll
    for (int cp = 0; cp < 4; ++cp) {
      #pragma unroll
      for (int i = 0; i < 8; ++i) Vt[(cp * 8 + i) * 72 + lane] = vr[cp][i];
    }
    f32x4 A1v[4], asv[4], bsv[4];
    #pragma unroll
    for (int mt = 0; mt < 4; ++mt) {
      const int pp = p0 + mt * 16 + g * 4;
      A1v[mt] = *(const f32x4*)(A1 + bhw + pp);
      asv[mt] = *(const f32x4*)(asd + pp);
      bsv[mt] = *(const f32x4*)(bsd + pp);
    }
    uint2 pwv[3][4];
    #pragma unroll
    for (int nt = 0; nt < 3; ++nt) {
      const float* mrow = masks + ((size_t)b * NC_ + cls[nt]) * HW_;
      f32x4 att[4];
      #pragma unroll
      for (int mt = 0; mt < 4; ++mt) {
        const f32x4 mk = *(const f32x4*)(mrow + p0 + mt * 16 + g * 4);
        att[mt] = A1v[mt] * cwq[nt] + asv[mt] * cbq[nt] + sa[nt][mt] * mk * bsv[mt];
      }
      float mx = -1e30f;
      #pragma unroll
      for (int mt = 0; mt < 4; ++mt)
        mx = fmaxf(mx, fmaxf(fmaxf(att[mt][0], att[mt][1]), fmaxf(att[mt][2], att[mt][3])));
      mx = fmaxf(mx, __shfl_xor(mx, 16));
      mx = fmaxf(mx, __shfl_xor(mx, 32));
      const float newm = fmaxf(m_r[nt], mx);
      const float sc = __expf(m_r[nt] - newm);
      m_r[nt] = newm;
      scv[nt] = sc;
      float sum = 0.f;
      #pragma unroll
      for (int mt = 0; mt < 4; ++mt) {
        #pragma unroll
        for (int i = 0; i < 4; ++i) att[mt][i] = __expf(att[mt][i] - newm);
        sum += (att[mt][0] + att[mt][1]) + (att[mt][2] + att[mt][3]);
        pwv[nt][mt].x = cvtpk_bf16(att[mt][0], att[mt][1]);
        pwv[nt][mt].y = cvtpk_bf16(att[mt][2], att[mt][3]);
      }
      sum += __shfl_xor(sum, 16);
      sum += __shfl_xor(sum, 32);
      l_r[nt] = l_r[nt] * sc + sum;
    }
    #pragma unroll
    for (int nt = 0; nt < 3; ++nt)
      #pragma unroll
      for (int dt = 0; dt < 2; ++dt)
        #pragma unroll
        for (int r = 0; r < 4; ++r) acc_oT[nt][dt][r] *= scv[nt];
#if HAVE_MFMA16
    __builtin_amdgcn_s_setprio(1);
    #pragma unroll
    for (int mt = 0; mt < 4; ++mt) {
      s4b vf[2];
      #pragma unroll
      for (int dt = 0; dt < 2; ++dt)
        vf[dt] = *(const s4b*)&Vt[(dt * 16 + c) * 72 + mt * 16 + g * 4];
      #pragma unroll
      for (int nt = 0; nt < 3; ++nt)
        #pragma unroll
        for (int dt = 0; dt < 2; ++dt)
          acc_oT[nt][dt] = __builtin_amdgcn_mfma_f32_16x16x16bf16_1k(
              vf[dt], *(const s4b*)&pwv[nt][mt], acc_oT[nt][dt], 0, 0, 0);
    }
    __builtin_amdgcn_s_setprio(0);
#else
    #pragma unroll
    for (int nt = 0; nt < 3; ++nt)
      #pragma unroll
      for (int mt = 0; mt < 4; ++mt)
        *(uint2*)&Pl[(nt * 16 + c) * 72 + mt * 16 + g * 4] = pwv[nt][mt];
    #pragma unroll
    for (int ks = 0; ks < 2; ++ks) {
      s8b pf[3], vf2[2];
      #pragma unroll
      for (int nt = 0; nt < 3; ++nt)
        pf[nt] = *(const s8b*)&Pl[(nt * 16 + c) * 72 + ks * 32 + g * 8];
      #pragma unroll
      for (int dt = 0; dt < 2; ++dt)
        vf2[dt] = *(const s8b*)&Vt[(dt * 16 + c) * 72 + ks * 32 + g * 8];
      #pragma unroll
      for (int nt = 0; nt < 3; ++nt)
        #pragma unroll
        for (int dt = 0; dt < 2; ++dt)
          acc_oT[nt][dt] = __builtin_amdgcn_mfma_f32_16x16x32_bf16(vf2[dt], pf[nt], acc_oT[nt][dt], 0, 0, 0);
    }
#endif
  }
  const int pidx = ((b * NH_ + n) * NPART_) + ch;
  #pragma unroll
  for (int nt = 0; nt < 3; ++nt) {
    const int q = nt * 16 + c;
    if (q < Q_) {
      #pragma unroll
      for (int dt = 0; dt < 2; ++dt)
        *(f32x4*)&pacc[((size_t)pidx * Q_ + q) * HD_ + dt * 16 + g * 4] = acc_oT[nt][dt];
    }
  }
  if (g == 0) {
    #pragma unroll
    for (int nt = 0; nt < 3; ++nt) {
      const int q = nt * 16 + c;
      if (q < Q_) {
        pm[(size_t)pidx * Q_ + q] = m_r[nt];
        pl[(size_t)pidx * Q_ + q] = l_r[nt];
      }
    }
  }
}

// ---------- cfinal: attn_comb fused with final projection ----------
__global__ __launch_bounds__(256)
void cfinal(const float* __restrict__ pacc, const float* __restrict__ pm,
            const float* __restrict__ pl, const float* __restrict__ ow,
            const float* __restrict__ ob, float* __restrict__ out) {
  __shared__ float xs[E_];
  const int row = blockIdx.x;            // b*Q + q
  const int q = row % Q_;
  const int b = row / Q_;
  const int e = threadIdx.x;
  const int n = e >> 5, d = e & 31;
  const int base = (b * NH_ + n) * NPART_;
  float M = -1e30f;
  #pragma unroll
  for (int cc = 0; cc < NPART_; ++cc) M = fmaxf(M, pm[(size_t)(base + cc) * Q_ + q]);
  float L = 0.f, O = 0.f;
  #pragma unroll
  for (int cc = 0; cc < NPART_; ++cc) {
    const size_t o2 = (size_t)(base + cc) * Q_ + q;
    const float w = __expf(pm[o2] - M);
    L += pl[o2] * w;
    O += pacc[o2 * HD_ + d] * w;
  }
  xs[e] = O / L;
  __syncthreads();
  float acc = ob[e];
  #pragma unroll 8
  for (int c = 0; c < E_; ++c) acc += xs[c] * ow[(size_t)c * E_ + e];
  out[(size_t)row * E_ + e] = acc;
}

extern "C" void kernel_launch(void* const* d_in, const int* in_sizes, int n_in,
                              void* d_out, int out_size, void* d_ws, size_t ws_size,
                              hipStream_t stream) {
  (void)in_sizes; (void)n_in; (void)out_size; (void)ws_size;
  const float* qp    = (const float*)d_in[0];
  const float* img   = (const float*)d_in[1];
  const float* msk   = (const float*)d_in[2];
  const float* masks = (const float*)d_in[3];
  const float* ln_g  = (const float*)d_in[4];
  const float* ln_b  = (const float*)d_in[5];
  const float* qw    = (const float*)d_in[6];
  const float* qb    = (const float*)d_in[7];
  const float* x1w   = (const float*)d_in[8];
  const float* x1b   = (const float*)d_in[9];
  const float* x2w   = (const float*)d_in[10];
  const float* x2b   = (const float*)d_in[11];
  const float* ln2g  = (const float*)d_in[12];
  const float* ln2b  = (const float*)d_in[13];
  const float* dww   = (const float*)d_in[14];
  const float* dwb   = (const float*)d_in[15];
  const float* kw    = (const float*)d_in[16];
  const float* kb    = (const float*)d_in[17];
  const float* vw    = (const float*)d_in[18];
  const float* vb    = (const float*)d_in[19];
  const float* icw   = (const float*)d_in[20];
  const float* icb   = (const float*)d_in[21];
  const float* mcw   = (const float*)d_in[22];
  const float* mcb   = (const float*)d_in[23];
  const float* ipw   = (const float*)d_in[24];
  const float* ipb   = (const float*)d_in[25];
  const float* mpw   = (const float*)d_in[26];
  const float* mpb   = (const float*)d_in[27];
  const float* cw    = (const float*)d_in[28];
  const float* cb    = (const float*)d_in[29];
  const float* alpha = (const float*)d_in[30];
  const float* beta  = (const float*)d_in[31];
  const float* ow    = (const float*)d_in[32];
  const float* ob    = (const float*)d_in[33];

  char* wsb = (char*)d_ws;
  const size_t MB = 1024 * 1024;
  unsigned short* xf    = (unsigned short*)(wsb);            // dwconv output (32MB)
  unsigned short* x1buf = (unsigned short*)(wsb + 42 * MB);  // 32MB
  unsigned short* x2    = (unsigned short*)(wsb + 76 * MB);  // 32MB; kv overlays after dwconv
  unsigned short* kv    = (unsigned short*)(wsb + 76 * MB);  // 64MB (76..140)
  unsigned short* wt1 = (unsigned short*)(wsb + 141 * MB);   // 256x320
  unsigned short* wt2 = wt1 + 256 * KP1_;                    // 256x256
  unsigned short* wtkv = wt2 + 256 * 256;                    // 512x256
  float* fb    = (float*)(wsb + 143 * MB);
  float* kvbias = fb;                                        // 512
  float* qbuf  = kvbias + 512;
  float* meanb = qbuf + (size_t)B_ * Q_ * E_;
  float* rstdb = meanb + (size_t)B_ * HW_;
  float* timg  = rstdb + (size_t)B_ * HW_;
  float* tmsk  = timg + (size_t)B_ * HW_;
  float* A1b   = tmsk + (size_t)B_ * HW_;
  float* asdb  = A1b + (size_t)B_ * HW_;
  float* bsdb  = asdb + HW_;
  float* pacc  = bsdb + HW_;
  float* pmb   = pacc + (size_t)B_ * NH_ * NPART_ * Q_ * HD_;
  float* plb   = pmb + (size_t)B_ * NH_ * NPART_ * Q_;
  float* partv = plb + (size_t)B_ * NH_ * NPART_ * Q_;       // 16*2*16*64

  // 1. misc1: wprep U q-branch U tvec  (xcat_t removed -> fused into hgemm1f)
  misc1<<<dim3(4 * KP1_ + 640 + 256), dim3(256), 0, stream>>>(
      x1w, x2w, kw, vw, kb, vb, wt1, wt2, wtkv, kvbias,
      img, msk, qp, ln_g, ln_b, qw, qb, qbuf,
      icw, icb, mcw, mcb, timg, tmsk);
  // 2. attvec partials (parallel)
  attvec_p<<<dim3(16, B_, 2), dim3(256), 0, stream>>>(timg, tmsk, ipw, mpw, partv);
  // 3. attbias reduce + A1/asd/bsd
  attbias2<<<dim3(B_), dim3(256), 0, stream>>>(partv, ipb, mpb, alpha, beta, A1b, asdb, bsdb);
  // 4. x1 = gelu(xcat @ W1^T + b1)  [fused transpose staging, padded As rows]
  hgemm1f<<<dim3(512 * 4), dim3(256), 0, stream>>>(img, msk, wt1, x1b, x1buf);
  // 5. x2 = x1 @ W2^T + b2
  hgemm<1, 256, 256, 4><<<dim3(512 * 4), dim3(256), 0, stream>>>(x1buf, wt2, x2b, x2);
  // 6. channel-LN stats
  rowstats<<<dim3(B_ * HW_ / 4), dim3(256), 0, stream>>>(x2, meanb, rstdb);
  // 7. depthwise 3x3 with fused LN -> xf (channel-split + async halo staging)
  dwconv_ln4<<<dim3(4, 16, B_ * 2), dim3(256), 0, stream>>>(x2, meanb, rstdb, ln2g, ln2b, dww, dwb, xf);
  // 8. fused k+v (N=512)
  hgemm<1, 256, KVS_, 8><<<dim3(512 * 8), dim3(256), 0, stream>>>(xf, wtkv, kvbias, kv);
  // 9. attention (XCD-local head groups, flattened grid)
  attn_mfma1w<<<dim3(CH2_ * NH_ * B_), dim3(64), 0, stream>>>(qbuf, kv, masks, A1b, asdb, bsdb,
                                                              cw, cb, pacc, pmb, plb);
  // 10. comb + final projection
  cfinal<<<dim3(B_ * Q_), dim3(256), 0, stream>>>(pacc, pmb, plb, ow, ob, (float*)d_out);
}

// Round 28
// 196.760 us; speedup vs baseline: 1.0183x; 1.0183x over previous
//
#include <hip/hip_runtime.h>
#include <math.h>

constexpr int B_ = 16, E_ = 256, NC_ = 8, Q_ = 40, H_ = 64, W_ = 64, HW_ = 4096;
constexpr int NH_ = 8, HD_ = 32, OF_ = 64;
constexpr int KP1_ = 320;          // padded K for gemm1 (E+NC=264 -> 320)
constexpr int NPART_ = 32;         // attention partials per (b,head)
constexpr int CH2_ = 32;           // attention chunks (1 wave each, 128 px)
constexpr int KVS_ = 512;          // kv buffer row stride (k 0..255, v 256..511)

typedef __attribute__((ext_vector_type(8))) unsigned short us8;
typedef __attribute__((ext_vector_type(8))) short s8b;     // bf16 MFMA frag (K=32)
typedef __attribute__((ext_vector_type(4))) short s4b;     // bf16 MFMA frag (K=16)
typedef __attribute__((ext_vector_type(4))) float f32x4;

__device__ __forceinline__ float gelu_f(float x) {
  return 0.5f * x * (1.0f + erff(x * 0.70710678118654752f));
}
__device__ __forceinline__ float bf2f(unsigned short u) {
  return __uint_as_float(((unsigned int)u) << 16);
}
__device__ __forceinline__ unsigned short f2bf(float f) {
  unsigned int u = __float_as_uint(f);
  u = u + 0x7fff + ((u >> 16) & 1);  // RNE
  return (unsigned short)(u >> 16);
}
// pack two f32 -> one u32 of 2 bf16 (lo=a, hi=b), RNE
__device__ __forceinline__ unsigned int cvtpk_bf16(float a, float b) {
  unsigned int r;
  asm("v_cvt_pk_bf16_f32 %0, %1, %2" : "=v"(r) : "v"(a), "v"(b));
  return r;
}
// async global->LDS 16B; LDS dest linear in lane (wave base + lane*16)
__device__ __forceinline__ void gl_lds16(const unsigned short* g, unsigned short* l) {
  __builtin_amdgcn_global_load_lds(
      (const __attribute__((address_space(1))) unsigned int*)g,
      (__attribute__((address_space(3))) unsigned int*)l, 16, 0, 0);
}

// ---------- misc1: wprep U q-branch(LN+GEMM) U tvec, range-dispatched ----------
// (xcat_t transpose removed -- fused into hgemm1f's A-staging)
__global__ __launch_bounds__(256)
void misc1(const float* __restrict__ w1, const float* __restrict__ w2,
           const float* __restrict__ wk, const float* __restrict__ wv,
           const float* __restrict__ kb, const float* __restrict__ vb,
           unsigned short* __restrict__ o1, unsigned short* __restrict__ o2,
           unsigned short* __restrict__ okv, float* __restrict__ kvbias,
           const float* __restrict__ img, const float* __restrict__ msk,
           const float* __restrict__ qp, const float* __restrict__ ln_g,
           const float* __restrict__ ln_b, const float* __restrict__ qw,
           const float* __restrict__ qb, float* __restrict__ qbuf,
           const float* __restrict__ icw, const float* __restrict__ icb,
           const float* __restrict__ mcw, const float* __restrict__ mcb,
           float* __restrict__ timg, float* __restrict__ tmsk) {
  __shared__ __align__(16) float smem[64 * 65];
  const int bid = blockIdx.x;
  const int t = threadIdx.x;
  if (bid < 4 * KP1_) {
    // ---- wprep ----
    const int which = bid / KP1_;
    const int k = bid % KP1_;
    const int n = t;
    if (which == 0) {
      float v = (k < 264) ? w1[(size_t)k * E_ + n] : 0.f;
      o1[(size_t)n * KP1_ + k] = f2bf(v);
    } else if (k < 256) {
      if (which == 1) {
        o2[(size_t)n * 256 + k] = f2bf(w2[(size_t)k * E_ + n]);
      } else if (which == 2) {
        okv[(size_t)n * 256 + k] = f2bf(wk[(size_t)k * E_ + n]);
        if (k == 0) kvbias[n] = kb[n];
      } else {
        okv[(size_t)(256 + n) * 256 + k] = f2bf(wv[(size_t)k * E_ + n]);
        if (k == 0) kvbias[256 + n] = vb[n];
      }
    }
  } else if (bid < 4 * KP1_ + 640) {
    // ---- q branch: LN + Linear ----
    const int row = bid - 4 * KP1_;
    float* xs = smem;
    float* rs = smem + 272;
    float* rs2 = smem + 280;
    float* sm = smem + 288;
    float x = qp[(size_t)row * E_ + t];
    float s = x, s2 = x * x;
    #pragma unroll
    for (int o = 32; o > 0; o >>= 1) { s += __shfl_down(s, o, 64); s2 += __shfl_down(s2, o, 64); }
    if ((t & 63) == 0) { rs[t >> 6] = s; rs2[t >> 6] = s2; }
    __syncthreads();
    if (t == 0) {
      float S = rs[0] + rs[1] + rs[2] + rs[3];
      float S2 = rs2[0] + rs2[1] + rs2[2] + rs2[3];
      float m = S * (1.0f / E_);
      sm[0] = m;
      sm[1] = rsqrtf(S2 * (1.0f / E_) - m * m + 1e-5f);
    }
    __syncthreads();
    x = (x - sm[0]) * sm[1] * ln_g[t] + ln_b[t];
    xs[t] = x;
    __syncthreads();
    float acc = qb[t];
    #pragma unroll 8
    for (int c = 0; c < E_; ++c) acc += xs[c] * qw[(size_t)c * E_ + t];
    qbuf[(size_t)row * E_ + t] = acc;
  } else {
    // ---- tvec: float4 over 4 pixels/lane ----
    const int id = bid - (4 * KP1_ + 640);
    const int b = id >> 4;
    const int chunk = id & 15;
    const int lane = t & 63, seg = t >> 6;
    const int p = chunk * 256 + lane * 4;
    f32x4 (*red)[64] = (f32x4(*)[64])smem;
    f32x4 s = (f32x4){0.f, 0.f, 0.f, 0.f};
    const float* ib = img + (size_t)b * E_ * HW_ + p;
    #pragma unroll 8
    for (int e = seg * 64; e < seg * 64 + 64; ++e) {
      const f32x4 v = *(const f32x4*)(ib + (size_t)e * HW_);
      s += v * icw[e];
    }
    red[seg][lane] = s;
    __syncthreads();
    if (seg == 0) {
      f32x4 tot = red[0][lane] + red[1][lane] + red[2][lane] + red[3][lane];
      #pragma unroll
      for (int j = 0; j < 4; ++j) tot[j] += icb[0];
      *(f32x4*)(timg + (size_t)b * HW_ + p) = tot;
      f32x4 s2;
      #pragma unroll
      for (int j = 0; j < 4; ++j) s2[j] = mcb[0];
      const float* mb = msk + (size_t)b * NC_ * HW_ + p;
      #pragma unroll
      for (int c = 0; c < NC_; ++c) {
        const f32x4 mv = *(const f32x4*)(mb + (size_t)c * HW_);
        s2 += mv * mcw[c];
      }
      *(f32x4*)(tmsk + (size_t)b * HW_ + p) = s2;
    }
  }
}

// ---------- hgemm: round-10 body + XCD-aware A-panel locality remap ----------
template<int EPI, int KP, int OSTR, int NN>
__global__ __launch_bounds__(256, 4)
void hgemm(const unsigned short* __restrict__ A, const unsigned short* __restrict__ Wt,
           const float* __restrict__ bias, unsigned short* __restrict__ out) {
  constexpr int NT = KP / 64;                     // 4 or 5 K-steps
  __shared__ __align__(16) unsigned short As[128 * 64];  // 16 KB
  __shared__ __align__(16) unsigned short Bs[64 * 64];   // 8 KB
  const int t = threadIdx.x;
  const int bid = blockIdx.x;
  const int xcd = bid & 7;
  const int grp = bid >> 3;
  const int m0 = ((grp / NN) * 8 + xcd) * 128;
  const int n0 = (grp % NN) * 64;
  const int w = t >> 6, lane = t & 63;
  const int c = lane & 15, g = lane >> 4;
  const int wm = (w & 1) * 64, wn = (w >> 1) * 32;

  f32x4 acc[4][2];
  #pragma unroll
  for (int i = 0; i < 4; ++i)
    #pragma unroll
    for (int j = 0; j < 2; ++j) acc[i][j] = (f32x4){0.f, 0.f, 0.f, 0.f};

  for (int kt = 0; kt < NT; ++kt) {
    if (kt) __syncthreads();
    #pragma unroll
    for (int i = 0; i < 4; ++i) {
      const int f = i * 256 + t;
      const int row = f >> 3, s = f & 7;
      gl_lds16(A + (size_t)(m0 + row) * KP + kt * 64 + (s ^ (row & 7)) * 8, As + f * 8);
    }
    #pragma unroll
    for (int i = 0; i < 2; ++i) {
      const int f = i * 256 + t;
      const int row = f >> 3, s = f & 7;
      gl_lds16(Wt + (size_t)(n0 + row) * KP + kt * 64 + (s ^ (row & 7)) * 8, Bs + f * 8);
    }
    __syncthreads();
    #pragma unroll
    for (int ks = 0; ks < 2; ++ks) {
      s8b af[4], bf[2];
      #pragma unroll
      for (int mf = 0; mf < 4; ++mf) {
        const int row = wm + mf * 16 + c;
        af[mf] = *(const s8b*)&As[row * 64 + ((ks * 4 + g) ^ (row & 7)) * 8];
      }
      #pragma unroll
      for (int nf = 0; nf < 2; ++nf) {
        const int row = wn + nf * 16 + c;
        bf[nf] = *(const s8b*)&Bs[row * 64 + ((ks * 4 + g) ^ (row & 7)) * 8];
      }
      #pragma unroll
      for (int mf = 0; mf < 4; ++mf)
        #pragma unroll
        for (int nf = 0; nf < 2; ++nf)
          acc[mf][nf] = __builtin_amdgcn_mfma_f32_16x16x32_bf16(af[mf], bf[nf], acc[mf][nf], 0, 0, 0);
    }
  }

  float bv[2];
  #pragma unroll
  for (int nf = 0; nf < 2; ++nf) bv[nf] = bias[n0 + wn + nf * 16 + c];
  __syncthreads();
  #pragma unroll
  for (int mf = 0; mf < 4; ++mf)
    #pragma unroll
    for (int r = 0; r < 4; ++r) {
      const int row = wm + mf * 16 + g * 4 + r;
      #pragma unroll
      for (int nf = 0; nf < 2; ++nf) {
        float v = acc[mf][nf][r] + bv[nf];
        if constexpr (EPI == 0) v = gelu_f(v);
        As[row * 64 + wn + nf * 16 + c] = f2bf(v);
      }
    }
  __syncthreads();
  #pragma unroll
  for (int i = 0; i < 4; ++i) {
    const int f = i * 256 + t;
    const int row = f >> 3, sl = f & 7;
    *(us8*)(out + (size_t)(m0 + row) * OSTR + n0 + sl * 8) = *(const us8*)&As[row * 64 + sl * 8];
  }
}

// ---------- hgemm1f: gemm1 with FUSED on-the-fly transpose of img/msk ----------
// A-source is fp32 [k][px]. As slot for (px, k-chunk c) = c ^ swz(px) with
// swz(px) = (px&7) ^ ((px>>3)&7). The extra (px>>3) term makes the STAGING
// writes sweep all 8 bank-quads within each 32-lane group (4 lanes/quad =
// b128 floor; round-26's (px&7)-only form was 16-way, 4.45M conflicts).
// Reads keep the round-26 2-way pattern (c=0..7 / 8..15 each span all quads).
__global__ __launch_bounds__(256, 4)
void hgemm1f(const float* __restrict__ img, const float* __restrict__ msk,
             const unsigned short* __restrict__ Wt,
             const float* __restrict__ bias, unsigned short* __restrict__ out) {
  constexpr int KP = KP1_;          // 320
  constexpr int NT = 5;
  constexpr int NN = 4;
  __shared__ __align__(16) unsigned short As[128 * 64];  // 16 KB
  __shared__ __align__(16) unsigned short Bs[64 * 64];   // 8 KB
  const int t = threadIdx.x;
  const int bid = blockIdx.x;
  const int xcd = bid & 7;
  const int grp = bid >> 3;
  const int m0 = ((grp / NN) * 8 + xcd) * 128;
  const int n0 = (grp % NN) * 64;
  const int b = m0 >> 12;           // batch (128 | 4096, never crosses)
  const int px0 = m0 & 4095;        // pixel base within batch
  const int w = t >> 6, lane = t & 63;
  const int c = lane & 15, g = lane >> 4;
  const int wm = (w & 1) * 64, wn = (w >> 1) * 32;
  const int pg = t & 31;            // 4-px group (0..31)
  const int kg = t >> 5;            // 8-k group (0..7)

  f32x4 acc[4][2];
  #pragma unroll
  for (int i = 0; i < 4; ++i)
    #pragma unroll
    for (int j = 0; j < 2; ++j) acc[i][j] = (f32x4){0.f, 0.f, 0.f, 0.f};

  for (int kt = 0; kt < NT; ++kt) {
    if (kt) __syncthreads();
    // B staging (async, bf16 weights prepped by wprep; keeps XOR swizzle)
    #pragma unroll
    for (int i = 0; i < 2; ++i) {
      const int f = i * 256 + t;
      const int row = f >> 3, s = f & 7;
      gl_lds16(Wt + (size_t)(n0 + row) * KP + kt * 64 + (s ^ (row & 7)) * 8, Bs + f * 8);
    }
    // A staging: 8 k-rows x 4 px per thread, fp32 -> bf16, transposed into As
    f32x4 ar[8];
    #pragma unroll
    for (int i = 0; i < 8; ++i) {
      const int k = kt * 64 + kg * 8 + i;
      if (k < 256)
        ar[i] = *(const f32x4*)(img + ((size_t)b * E_ + k) * HW_ + px0 + pg * 4);
      else if (k < 264)
        ar[i] = *(const f32x4*)(msk + ((size_t)b * NC_ + (k - 256)) * HW_ + px0 + pg * 4);
      else
        ar[i] = (f32x4){0.f, 0.f, 0.f, 0.f};   // zero pad (NaN-safe)
    }
    #pragma unroll
    for (int j = 0; j < 4; ++j) {
      const int px = pg * 4 + j;
      const int swz = (px & 7) ^ ((px >> 3) & 7);
      uint4 pk;
      pk.x = cvtpk_bf16(ar[0][j], ar[1][j]);
      pk.y = cvtpk_bf16(ar[2][j], ar[3][j]);
      pk.z = cvtpk_bf16(ar[4][j], ar[5][j]);
      pk.w = cvtpk_bf16(ar[6][j], ar[7][j]);
      *(uint4*)&As[px * 64 + ((kg ^ swz) * 8)] = pk;
    }
    __syncthreads();
    #pragma unroll
    for (int ks = 0; ks < 2; ++ks) {
      s8b af[4], bf[2];
      #pragma unroll
      for (int mf = 0; mf < 4; ++mf) {
        const int row = wm + mf * 16 + c;
        const int swz = (row & 7) ^ ((row >> 3) & 7);
        af[mf] = *(const s8b*)&As[row * 64 + (((ks * 4 + g) ^ swz) * 8)];
      }
      #pragma unroll
      for (int nf = 0; nf < 2; ++nf) {
        const int row = wn + nf * 16 + c;
        bf[nf] = *(const s8b*)&Bs[row * 64 + ((ks * 4 + g) ^ (row & 7)) * 8];
      }
      #pragma unroll
      for (int mf = 0; mf < 4; ++mf)
        #pragma unroll
        for (int nf = 0; nf < 2; ++nf)
          acc[mf][nf] = __builtin_amdgcn_mfma_f32_16x16x32_bf16(af[mf], bf[nf], acc[mf][nf], 0, 0, 0);
    }
  }

  float bv[2];
  #pragma unroll
  for (int nf = 0; nf < 2; ++nf) bv[nf] = bias[n0 + wn + nf * 16 + c];
  __syncthreads();
  #pragma unroll
  for (int mf = 0; mf < 4; ++mf)
    #pragma unroll
    for (int r = 0; r < 4; ++r) {
      const int row = wm + mf * 16 + g * 4 + r;
      #pragma unroll
      for (int nf = 0; nf < 2; ++nf) {
        float v = gelu_f(acc[mf][nf][r] + bv[nf]);
        As[row * 64 + wn + nf * 16 + c] = f2bf(v);   // linear scratch reuse
      }
    }
  __syncthreads();
  #pragma unroll
  for (int i = 0; i < 4; ++i) {
    const int f = i * 256 + t;
    const int row = f >> 3, sl = f & 7;
    *(us8*)(out + (size_t)(m0 + row) * 256 + n0 + sl * 8) = *(const us8*)&As[row * 64 + sl * 8];
  }
}

// ---------- rowstats ----------
__global__ __launch_bounds__(256)
void rowstats(const unsigned short* __restrict__ X, float* __restrict__ mean,
              float* __restrict__ rstd) {
  const int row = blockIdx.x * 4 + (threadIdx.x >> 6);
  const int lane = threadIdx.x & 63;
  const uint2 u = *(const uint2*)(X + (size_t)row * E_ + lane * 4);
  float a = bf2f(u.x & 0xffff), b = bf2f(u.x >> 16);
  float c = bf2f(u.y & 0xffff), d = bf2f(u.y >> 16);
  float s = a + b + c + d;
  float s2 = a * a + b * b + c * c + d * d;
  #pragma unroll
  for (int o = 32; o > 0; o >>= 1) { s += __shfl_down(s, o, 64); s2 += __shfl_down(s2, o, 64); }
  if (lane == 0) {
    const float m = s * (1.0f / E_);
    mean[row] = m;
    rstd[row] = rsqrtf(s2 * (1.0f / E_) - m * m + 1e-5f);
  }
}

// ---------- attvec_p: parallel partials for att_image/att_mask ----------
__global__ __launch_bounds__(256)
void attvec_p(const float* __restrict__ timg, const float* __restrict__ tmsk,
              const float* __restrict__ ipw, const float* __restrict__ mpw,
              float* __restrict__ part) {
  const int chunk = blockIdx.x;
  const int b = blockIdx.y;
  const int mat = blockIdx.z;
  const int o = threadIdx.x & 63, ps = threadIdx.x >> 6;
  const float* tv = (mat ? tmsk : timg) + (size_t)b * HW_ + chunk * 256;
  const float* wp = (mat ? mpw : ipw) + (size_t)chunk * 256 * OF_;
  float s = 0.f;
  #pragma unroll 8
  for (int i = 0; i < 64; ++i) {
    const int p = ps * 64 + i;
    s += tv[p] * wp[(size_t)p * OF_ + o];
  }
  __shared__ float red[4][64];
  red[ps][o] = s;
  __syncthreads();
  if (ps == 0)
    part[(((size_t)b * 2 + mat) * 16 + chunk) * OF_ + o] =
        red[0][o] + red[1][o] + red[2][o] + red[3][o];
}

// ---------- attbias2: reduce partials -> ai/am in LDS -> A1/asd/bsd ----------
__global__ __launch_bounds__(256)
void attbias2(const float* __restrict__ part, const float* __restrict__ ipb,
              const float* __restrict__ mpb, const float* __restrict__ alpha,
              const float* __restrict__ beta, float* __restrict__ A1,
              float* __restrict__ asd, float* __restrict__ bsd) {
  __shared__ float aiL[64], amL[64];
  const int b = blockIdx.x;
  const int t = threadIdx.x;
  if (t < 128) {
    const int mat = t >> 6, o = t & 63;
    float v = (mat ? mpb : ipb)[o];
    #pragma unroll
    for (int c = 0; c < 16; ++c)
      v += part[(((size_t)b * 2 + mat) * 16 + c) * OF_ + o];
    if (mat) amL[o] = v; else aiL[o] = v;
  }
  __syncthreads();
  const float scl = 0.17677669529663687f;  // 1/sqrt(32)
  #pragma unroll
  for (int it = 0; it < 16; ++it) {
    const int p = it * 256 + t;
    A1[(size_t)b * HW_ + p] = aiL[p >> 6] * amL[p & 63] * alpha[p] * scl;
    if (b == 0) {
      asd[p] = alpha[p] * scl;
      bsd[p] = beta[p] * scl;
    }
  }
}

// ---------- dwconv_ln4: channel-split blocks + ASYNC LDS halo staging ----------
__global__ __launch_bounds__(256, 4)
void dwconv_ln4(const unsigned short* __restrict__ X2, const float* __restrict__ mean,
                const float* __restrict__ rstd, const float* __restrict__ g2,
                const float* __restrict__ b2, const float* __restrict__ wgt,
                const float* __restrict__ cbias, unsigned short* __restrict__ out) {
  __shared__ __align__(16) unsigned short xsh[108 * 128];  // 27648 B
  __shared__ float msh[108], rsh[108];
  const int t = threadIdx.x;
  const int w0 = blockIdx.x * 16;
  const int h0 = blockIdx.y * 4;
  const int b = blockIdx.z >> 1;
  const int dh = blockIdx.z & 1;
  const int dl = t & 127;            // local channel
  const int cg = t >> 7;             // col-group (8 cols each)
  const int dgl = dh * 128 + dl;     // global channel
  const size_t bbase = (size_t)b * HW_;
  for (int f = t; f < 108 * 16; f += 256) {
    const int pix = f >> 4, sl = f & 15;
    const int s = pix / 18, i = pix % 18;
    const int hh = h0 - 1 + s, ww = w0 - 1 + i;
    const bool ok = (hh >= 0 && hh < H_ && ww >= 0 && ww < W_);
    const size_t p = ok ? (bbase + hh * W_ + ww) : bbase;   // clamp; never read if !ok
    gl_lds16(X2 + p * E_ + dh * 128 + sl * 8, &xsh[f * 8]);
  }
  if (t < 108) {
    const int pix = t;
    const int s = pix / 18, i = pix % 18;
    const int hh = h0 - 1 + s, ww = w0 - 1 + i;
    if (hh >= 0 && hh < H_ && ww >= 0 && ww < W_) {
      const size_t p = bbase + hh * W_ + ww;
      msh[pix] = mean[p];
      rsh[pix] = rstd[p];
    } else {
      msh[pix] = 0.f;
      rsh[pix] = 0.f;
    }
  }
  float wq[9];
  #pragma unroll
  for (int i = 0; i < 9; ++i) wq[i] = wgt[i * E_ + dgl];
  const float gg = g2[dgl], bb = b2[dgl], bias = cbias[dgl];
  __syncthreads();   // drains gl_lds16 (vmcnt) + msh/rsh writes
  float o[4][8];
  #pragma unroll
  for (int oy = 0; oy < 4; ++oy)
    #pragma unroll
    for (int j = 0; j < 8; ++j) o[oy][j] = bias;
  #pragma unroll
  for (int s = 0; s < 6; ++s) {
    const int hh = h0 - 1 + s;
    if (hh < 0 || hh >= H_) continue;
    float r[10];
    #pragma unroll
    for (int i = 0; i < 10; ++i) {
      const int rc = cg * 8 + i;          // region col 0..17
      const int ww = w0 - 1 + rc;
      if (ww >= 0 && ww < W_) {
        const int pix = s * 18 + rc;
        const float x = bf2f(xsh[pix * 128 + dl]);
        r[i] = (x - msh[pix]) * rsh[pix] * gg + bb;
      } else r[i] = 0.f;
    }
    #pragma unroll
    for (int ky = 0; ky < 3; ++ky) {
      const int oy = s - ky;
      if (oy < 0 || oy >= 4) continue;
      const float w_0 = wq[ky * 3], w_1 = wq[ky * 3 + 1], w_2 = wq[ky * 3 + 2];
      #pragma unroll
      for (int j = 0; j < 8; ++j)
        o[oy][j] += r[j] * w_0 + r[j + 1] * w_1 + r[j + 2] * w_2;
    }
  }
  #pragma unroll
  for (int oy = 0; oy < 4; ++oy) {
    const size_t ob_ = bbase + (h0 + oy) * W_ + w0 + cg * 8;
    #pragma unroll
    for (int j = 0; j < 8; ++j) out[(ob_ + j) * E_ + dgl] = f2bf(o[oy][j]);
  }
}

#if __has_builtin(__builtin_amdgcn_mfma_f32_16x16x16bf16_1k)
#define HAVE_MFMA16 1
#else
#define HAVE_MFMA16 0
#endif

// ---------- MFMA flash attention: O^T formulation + XCD-local head groups ----------
__global__ __launch_bounds__(64)
void attn_mfma1w(const float* __restrict__ qbuf, const unsigned short* __restrict__ kv,
                 const float* __restrict__ masks,
                 const float* __restrict__ A1, const float* __restrict__ asd,
                 const float* __restrict__ bsd, const float* __restrict__ cw,
                 const float* __restrict__ cb,
                 float* __restrict__ pacc, float* __restrict__ pm, float* __restrict__ pl) {
  const int bid = blockIdx.x;
  const int xcd = bid & 7;
  const int n = (bid >> 3) & 7;
  const int pb = ((bid >> 6) << 3) | xcd;   // 0..511 = (ch,b)
  const int ch = pb & 31;
  const int b = pb >> 5;
  const int lane = threadIdx.x;
  const int c = lane & 15, g = lane >> 4;
  __shared__ __align__(16) unsigned short Vt[32 * 72];
#if !HAVE_MFMA16
  __shared__ __align__(16) unsigned short Pl[48 * 72];
#endif

  const size_t bhw = (size_t)b * HW_;
  const int koff = n * HD_;
  const int voff = 256 + koff;
  const int pbase = ch * 128;

  s8b kf2[2][4];
  #pragma unroll
  for (int tile = 0; tile < 2; ++tile) {
    const int p0 = pbase + tile * 64;
    #pragma unroll
    for (int mt = 0; mt < 4; ++mt)
      kf2[tile][mt] = *(const s8b*)(kv + (bhw + p0 + mt * 16 + c) * KVS_ + koff + g * 8);
  }

  s8b qf[3];
  float cwq[3], cbq[3];
  int cls[3];
  #pragma unroll
  for (int nt = 0; nt < 3; ++nt) {
    const int q = nt * 16 + c;
    unsigned short tmp[8];
    if (q < Q_) {
      const float* qp = qbuf + ((size_t)b * Q_ + q) * E_ + koff + g * 8;
      const float4 f0 = *(const float4*)qp;
      const float4 f1 = *(const float4*)(qp + 4);
      tmp[0] = f2bf(f0.x); tmp[1] = f2bf(f0.y); tmp[2] = f2bf(f0.z); tmp[3] = f2bf(f0.w);
      tmp[4] = f2bf(f1.x); tmp[5] = f2bf(f1.y); tmp[6] = f2bf(f1.z); tmp[7] = f2bf(f1.w);
      cwq[nt] = cw[q]; cbq[nt] = cb[q];
    } else {
      #pragma unroll
      for (int i = 0; i < 8; ++i) tmp[i] = 0;
      cwq[nt] = 0.f; cbq[nt] = 0.f;
    }
    qf[nt] = *(const s8b*)tmp;
    cls[nt] = min(q / 5, NC_ - 1);
  }

  f32x4 acc_oT[3][2];
  #pragma unroll
  for (int qt = 0; qt < 3; ++qt)
    #pragma unroll
    for (int dt = 0; dt < 2; ++dt) acc_oT[qt][dt] = (f32x4){0.f, 0.f, 0.f, 0.f};
  float m_r[3] = {-1e30f, -1e30f, -1e30f};
  float l_r[3] = {0.f, 0.f, 0.f};
  float scv[3] = {1.f, 1.f, 1.f};

  #pragma unroll
  for (int tile = 0; tile < 2; ++tile) {
    const int p0 = pbase + tile * 64;
    us8 vr[4];
    #pragma unroll
    for (int cp = 0; cp < 4; ++cp)
      vr[cp] = *(const us8*)(kv + (bhw + p0 + lane) * KVS_ + voff + cp * 8);
    f32x4 sa[3][4];
    __builtin_amdgcn_s_setprio(1);
    #pragma unroll
    for (int nt = 0; nt < 3; ++nt)
      #pragma unroll
      for (int mt = 0; mt < 4; ++mt)
        sa[nt][mt] = __builtin_amdgcn_mfma_f32_16x16x32_bf16(kf2[tile][mt], qf[nt],
                     (f32x4){0.f, 0.f, 0.f, 0.f}, 0, 0, 0);
    __builtin_amdgcn_s_setprio(0);
    #pragma unroll
    for (int cp = 0; cp < 4; ++cp) {
      #pragma unroll
      for (int i = 0; i < 8; ++i) Vt[(cp * 8 + i) * 72 + lane] = vr[cp][i];
    }
    f32x4 A1v[4], asv[4], bsv[4];
    #pragma unroll
    for (int mt = 0; mt < 4; ++mt) {
      const int pp = p0 + mt * 16 + g * 4;
      A1v[mt] = *(const f32x4*)(A1 + bhw + pp);
      asv[mt] = *(const f32x4*)(asd + pp);
      bsv[mt] = *(const f32x4*)(bsd + pp);
    }
    uint2 pwv[3][4];
    #pragma unroll
    for (int nt = 0; nt < 3; ++nt) {
      const float* mrow = masks + ((size_t)b * NC_ + cls[nt]) * HW_;
      f32x4 att[4];
      #pragma unroll
      for (int mt = 0; mt < 4; ++mt) {
        const f32x4 mk = *(const f32x4*)(mrow + p0 + mt * 16 + g * 4);
        att[mt] = A1v[mt] * cwq[nt] + asv[mt] * cbq[nt] + sa[nt][mt] * mk * bsv[mt];
      }
      float mx = -1e30f;
      #pragma unroll
      for (int mt = 0; mt < 4; ++mt)
        mx = fmaxf(mx, fmaxf(fmaxf(att[mt][0], att[mt][1]), fmaxf(att[mt][2], att[mt][3])));
      mx = fmaxf(mx, __shfl_xor(mx, 16));
      mx = fmaxf(mx, __shfl_xor(mx, 32));
      const float newm = fmaxf(m_r[nt], mx);
      const float sc = __expf(m_r[nt] - newm);
      m_r[nt] = newm;
      scv[nt] = sc;
      float sum = 0.f;
      #pragma unroll
      for (int mt = 0; mt < 4; ++mt) {
        #pragma unroll
        for (int i = 0; i < 4; ++i) att[mt][i] = __expf(att[mt][i] - newm);
        sum += (att[mt][0] + att[mt][1]) + (att[mt][2] + att[mt][3]);
        pwv[nt][mt].x = cvtpk_bf16(att[mt][0], att[mt][1]);
        pwv[nt][mt].y = cvtpk_bf16(att[mt][2], att[mt][3]);
      }
      sum += __shfl_xor(sum, 16);
      sum += __shfl_xor(sum, 32);
      l_r[nt] = l_r[nt] * sc + sum;
    }
    #pragma unroll
    for (int nt = 0; nt < 3; ++nt)
      #pragma unroll
      for (int dt = 0; dt < 2; ++dt)
        #pragma unroll
        for (int r = 0; r < 4; ++r) acc_oT[nt][dt][r] *= scv[nt];
#if HAVE_MFMA16
    __builtin_amdgcn_s_setprio(1);
    #pragma unroll
    for (int mt = 0; mt < 4; ++mt) {
      s4b vf[2];
      #pragma unroll
      for (int dt = 0; dt < 2; ++dt)
        vf[dt] = *(const s4b*)&Vt[(dt * 16 + c) * 72 + mt * 16 + g * 4];
      #pragma unroll
      for (int nt = 0; nt < 3; ++nt)
        #pragma unroll
        for (int dt = 0; dt < 2; ++dt)
          acc_oT[nt][dt] = __builtin_amdgcn_mfma_f32_16x16x16bf16_1k(
              vf[dt], *(const s4b*)&pwv[nt][mt], acc_oT[nt][dt], 0, 0, 0);
    }
    __builtin_amdgcn_s_setprio(0);
#else
    #pragma unroll
    for (int nt = 0; nt < 3; ++nt)
      #pragma unroll
      for (int mt = 0; mt < 4; ++mt)
        *(uint2*)&Pl[(nt * 16 + c) * 72 + mt * 16 + g * 4] = pwv[nt][mt];
    #pragma unroll
    for (int ks = 0; ks < 2; ++ks) {
      s8b pf[3], vf2[2];
      #pragma unroll
      for (int nt = 0; nt < 3; ++nt)
        pf[nt] = *(const s8b*)&Pl[(nt * 16 + c) * 72 + ks * 32 + g * 8];
      #pragma unroll
      for (int dt = 0; dt < 2; ++dt)
        vf2[dt] = *(const s8b*)&Vt[(dt * 16 + c) * 72 + ks * 32 + g * 8];
      #pragma unroll
      for (int nt = 0; nt < 3; ++nt)
        #pragma unroll
        for (int dt = 0; dt < 2; ++dt)
          acc_oT[nt][dt] = __builtin_amdgcn_mfma_f32_16x16x32_bf16(vf2[dt], pf[nt], acc_oT[nt][dt], 0, 0, 0);
    }
#endif
  }
  const int pidx = ((b * NH_ + n) * NPART_) + ch;
  #pragma unroll
  for (int nt = 0; nt < 3; ++nt) {
    const int q = nt * 16 + c;
    if (q < Q_) {
      #pragma unroll
      for (int dt = 0; dt < 2; ++dt)
        *(f32x4*)&pacc[((size_t)pidx * Q_ + q) * HD_ + dt * 16 + g * 4] = acc_oT[nt][dt];
    }
  }
  if (g == 0) {
    #pragma unroll
    for (int nt = 0; nt < 3; ++nt) {
      const int q = nt * 16 + c;
      if (q < Q_) {
        pm[(size_t)pidx * Q_ + q] = m_r[nt];
        pl[(size_t)pidx * Q_ + q] = l_r[nt];
      }
    }
  }
}

// ---------- cfinal: attn_comb fused with final projection ----------
__global__ __launch_bounds__(256)
void cfinal(const float* __restrict__ pacc, const float* __restrict__ pm,
            const float* __restrict__ pl, const float* __restrict__ ow,
            const float* __restrict__ ob, float* __restrict__ out) {
  __shared__ float xs[E_];
  const int row = blockIdx.x;            // b*Q + q
  const int q = row % Q_;
  const int b = row / Q_;
  const int e = threadIdx.x;
  const int n = e >> 5, d = e & 31;
  const int base = (b * NH_ + n) * NPART_;
  float M = -1e30f;
  #pragma unroll
  for (int cc = 0; cc < NPART_; ++cc) M = fmaxf(M, pm[(size_t)(base + cc) * Q_ + q]);
  float L = 0.f, O = 0.f;
  #pragma unroll
  for (int cc = 0; cc < NPART_; ++cc) {
    const size_t o2 = (size_t)(base + cc) * Q_ + q;
    const float w = __expf(pm[o2] - M);
    L += pl[o2] * w;
    O += pacc[o2 * HD_ + d] * w;
  }
  xs[e] = O / L;
  __syncthreads();
  float acc = ob[e];
  #pragma unroll 8
  for (int c = 0; c < E_; ++c) acc += xs[c] * ow[(size_t)c * E_ + e];
  out[(size_t)row * E_ + e] = acc;
}

extern "C" void kernel_launch(void* const* d_in, const int* in_sizes, int n_in,
                              void* d_out, int out_size, void* d_ws, size_t ws_size,
                              hipStream_t stream) {
  (void)in_sizes; (void)n_in; (void)out_size; (void)ws_size;
  const float* qp    = (const float*)d_in[0];
  const float* img   = (const float*)d_in[1];
  const float* msk   = (const float*)d_in[2];
  const float* masks = (const float*)d_in[3];
  const float* ln_g  = (const float*)d_in[4];
  const float* ln_b  = (const float*)d_in[5];
  const float* qw    = (const float*)d_in[6];
  const float* qb    = (const float*)d_in[7];
  const float* x1w   = (const float*)d_in[8];
  const float* x1b   = (const float*)d_in[9];
  const float* x2w   = (const float*)d_in[10];
  const float* x2b   = (const float*)d_in[11];
  const float* ln2g  = (const float*)d_in[12];
  const float* ln2b  = (const float*)d_in[13];
  const float* dww   = (const float*)d_in[14];
  const float* dwb   = (const float*)d_in[15];
  const float* kw    = (const float*)d_in[16];
  const float* kb    = (const float*)d_in[17];
  const float* vw    = (const float*)d_in[18];
  const float* vb    = (const float*)d_in[19];
  const float* icw   = (const float*)d_in[20];
  const float* icb   = (const float*)d_in[21];
  const float* mcw   = (const float*)d_in[22];
  const float* mcb   = (const float*)d_in[23];
  const float* ipw   = (const float*)d_in[24];
  const float* ipb   = (const float*)d_in[25];
  const float* mpw   = (const float*)d_in[26];
  const float* mpb   = (const float*)d_in[27];
  const float* cw    = (const float*)d_in[28];
  const float* cb    = (const float*)d_in[29];
  const float* alpha = (const float*)d_in[30];
  const float* beta  = (const float*)d_in[31];
  const float* ow    = (const float*)d_in[32];
  const float* ob    = (const float*)d_in[33];

  char* wsb = (char*)d_ws;
  const size_t MB = 1024 * 1024;
  unsigned short* xf    = (unsigned short*)(wsb);            // dwconv output (32MB)
  unsigned short* x1buf = (unsigned short*)(wsb + 42 * MB);  // 32MB
  unsigned short* x2    = (unsigned short*)(wsb + 76 * MB);  // 32MB; kv overlays after dwconv
  unsigned short* kv    = (unsigned short*)(wsb + 76 * MB);  // 64MB (76..140)
  unsigned short* wt1 = (unsigned short*)(wsb + 141 * MB);   // 256x320
  unsigned short* wt2 = wt1 + 256 * KP1_;                    // 256x256
  unsigned short* wtkv = wt2 + 256 * 256;                    // 512x256
  float* fb    = (float*)(wsb + 143 * MB);
  float* kvbias = fb;                                        // 512
  float* qbuf  = kvbias + 512;
  float* meanb = qbuf + (size_t)B_ * Q_ * E_;
  float* rstdb = meanb + (size_t)B_ * HW_;
  float* timg  = rstdb + (size_t)B_ * HW_;
  float* tmsk  = timg + (size_t)B_ * HW_;
  float* A1b   = tmsk + (size_t)B_ * HW_;
  float* asdb  = A1b + (size_t)B_ * HW_;
  float* bsdb  = asdb + HW_;
  float* pacc  = bsdb + HW_;
  float* pmb   = pacc + (size_t)B_ * NH_ * NPART_ * Q_ * HD_;
  float* plb   = pmb + (size_t)B_ * NH_ * NPART_ * Q_;
  float* partv = plb + (size_t)B_ * NH_ * NPART_ * Q_;       // 16*2*16*64

  // 1. misc1: wprep U q-branch U tvec  (xcat_t removed -> fused into hgemm1f)
  misc1<<<dim3(4 * KP1_ + 640 + 256), dim3(256), 0, stream>>>(
      x1w, x2w, kw, vw, kb, vb, wt1, wt2, wtkv, kvbias,
      img, msk, qp, ln_g, ln_b, qw, qb, qbuf,
      icw, icb, mcw, mcb, timg, tmsk);
  // 2. attvec partials (parallel)
  attvec_p<<<dim3(16, B_, 2), dim3(256), 0, stream>>>(timg, tmsk, ipw, mpw, partv);
  // 3. attbias reduce + A1/asd/bsd
  attbias2<<<dim3(B_), dim3(256), 0, stream>>>(partv, ipb, mpb, alpha, beta, A1b, asdb, bsdb);
  // 4. x1 = gelu(xcat @ W1^T + b1)  [fused transpose staging, double-XOR swizzle]
  hgemm1f<<<dim3(512 * 4), dim3(256), 0, stream>>>(img, msk, wt1, x1b, x1buf);
  // 5. x2 = x1 @ W2^T + b2
  hgemm<1, 256, 256, 4><<<dim3(512 * 4), dim3(256), 0, stream>>>(x1buf, wt2, x2b, x2);
  // 6. channel-LN stats
  rowstats<<<dim3(B_ * HW_ / 4), dim3(256), 0, stream>>>(x2, meanb, rstdb);
  // 7. depthwise 3x3 with fused LN -> xf (channel-split + async halo staging)
  dwconv_ln4<<<dim3(4, 16, B_ * 2), dim3(256), 0, stream>>>(x2, meanb, rstdb, ln2g, ln2b, dww, dwb, xf);
  // 8. fused k+v (N=512)
  hgemm<1, 256, KVS_, 8><<<dim3(512 * 8), dim3(256), 0, stream>>>(xf, wtkv, kvbias, kv);
  // 9. attention (XCD-local head groups, flattened grid)
  attn_mfma1w<<<dim3(CH2_ * NH_ * B_), dim3(64), 0, stream>>>(qbuf, kv, masks, A1b, asdb, bsdb,
                                                              cw, cb, pacc, pmb, plb);
  // 10. comb + final projection
  cfinal<<<dim3(B_ * Q_), dim3(256), 0, stream>>>(pacc, pmb, plb, ow, ob, (float*)d_out);
}